// Round 26
// baseline (151.219 us; speedup 1.0000x reference)
//
#include <hip/hip_runtime.h>

#define H_ 96
#define W_ 96
#define NV (H_ * W_)      // 9216
#define NT 1024
#define WELEM 576
#define NSUB 9
#define ARENA_BYTES 136192

__device__ __forceinline__ float keyToFloat(unsigned int k) {
  return __uint_as_float((k & 0x80000000u) ? (k ^ 0x80000000u) : ~k);
}
__device__ __forceinline__ unsigned int bitsToKey(unsigned int b) {
  return b ^ ((b & 0x80000000u) ? 0xFFFFFFFFu : 0x80000000u);
}

__global__ __launch_bounds__(NT, 1)
void topo_pk(const float* __restrict__ x, float* __restrict__ out) {
  __shared__ unsigned int arenaW[ARENA_BYTES / 4];
  __shared__ unsigned int waveS[16];
  __shared__ unsigned int waveB[16];
  __shared__ double Td[16], Sd[16];
  unsigned char* arena = (unsigned char*)arenaW;
  unsigned int*   Ka    = (unsigned int*)(arena);
  unsigned int*   Kb    = (unsigned int*)(arena + 36864);
  unsigned short* Pa    = (unsigned short*)(arena + 73728);
  unsigned short* Pb    = (unsigned short*)(arena + 92160);
  unsigned int*   hist  = (unsigned int*)(arena + 110592);
  unsigned char*  incB  = (unsigned char*)(arena + 126976);
  unsigned short* parU  = (unsigned short*)(arena + 92160);   // P4 (Pb dead)
  unsigned int*   claim = (unsigned int*)(arena + 36864);     // P4 (Kb dead)

  const int tid = threadIdx.x;
  const int wv = tid >> 6, ln = tid & 63;
  const float* img = x + (size_t)blockIdx.x * NV;

  // ---- P2: 4-pass 8-bit LSD radix sort (stable via ballot multi-split) ----
  const int wbase = wv * WELEM;
  for (int pass = 0; pass < 4; ++pass) {
    const unsigned int*   Ks = (pass & 1) ? Kb : Ka;
    const unsigned short* Ps = (pass & 1) ? Pb : Pa;
    unsigned int*   Kd = (pass & 1) ? Ka : Kb;
    unsigned short* Pd = (pass & 1) ? Pa : Pb;
    const int sh = pass << 3;

    for (int i = tid; i < 16 * 256; i += NT) hist[i] = 0u;
    __syncthreads();

    unsigned kreg[NSUB];
    unsigned rk[NSUB];
    #pragma unroll
    for (int j = 0; j < NSUB; ++j) {
      const int e = wbase + j * 64 + ln;
      const unsigned k = (pass == 0) ? bitsToKey(__float_as_uint(img[e])) : Ks[e];
      kreg[j] = k;
      const unsigned d = (k >> sh) & 255u;
      unsigned long long mask = ~0ull;
      #pragma unroll
      for (int b = 0; b < 8; ++b) {
        const unsigned long long bb = __ballot((d >> b) & 1u);
        mask &= ((d >> b) & 1u) ? bb : ~bb;
      }
      const unsigned long long below = mask & ((1ull << ln) - 1ull);
      const unsigned old = hist[wv * 256 + d];
      rk[j] = (d << 16) | (old + (unsigned)__popcll(below));
      if (below == 0ull)
        hist[wv * 256 + d] = old + (unsigned)__popcll(mask);
    }
    __syncthreads();

    {
      unsigned v0, v1, v2, v3;
      const int s0 = tid * 4;
      v0 = hist[((s0 + 0) & 15) * 256 + ((s0 + 0) >> 4)];
      v1 = hist[((s0 + 1) & 15) * 256 + ((s0 + 1) >> 4)];
      v2 = hist[((s0 + 2) & 15) * 256 + ((s0 + 2) >> 4)];
      v3 = hist[((s0 + 3) & 15) * 256 + ((s0 + 3) >> 4)];
      const unsigned ts = v0 + v1 + v2 + v3;
      unsigned incl = ts;
      #pragma unroll
      for (int off = 1; off < 64; off <<= 1) {
        const unsigned n = (unsigned)__shfl_up((int)incl, off, 64);
        if (ln >= off) incl += n;
      }
      if (ln == 63) waveS[wv] = incl;
      __syncthreads();
      if (tid < 16) {
        unsigned s = 0;
        for (int q = 0; q < 16; ++q) { if (q == tid) break; s += waveS[q]; }
        waveB[tid] = s;
      }
      __syncthreads();
      unsigned run = waveB[wv] + (incl - ts);
      hist[((s0 + 0) & 15) * 256 + ((s0 + 0) >> 4)] = run; run += v0;
      hist[((s0 + 1) & 15) * 256 + ((s0 + 1) >> 4)] = run; run += v1;
      hist[((s0 + 2) & 15) * 256 + ((s0 + 2) >> 4)] = run; run += v2;
      hist[((s0 + 3) & 15) * 256 + ((s0 + 3) >> 4)] = run;
    }
    __syncthreads();

    #pragma unroll
    for (int j = 0; j < NSUB; ++j) {
      const int e = wbase + j * 64 + ln;
      const unsigned d = rk[j] >> 16;
      const unsigned dest = hist[wv * 256 + d] + (rk[j] & 0xFFFFu);
      Kd[dest] = kreg[j];
      Pd[dest] = (pass == 0) ? (unsigned short)e : Ps[e];
    }
    __syncthreads();
  }
  // sorted data in Ka / Pa

  // ---- P3: UF init + claim init + inclusion bits (coalesced img reads) ----
  for (int t = tid; t < NV; t += NT) parU[Pa[t]] = (unsigned short)(0x8000u | (unsigned)t);
  for (int i = tid; i < NV; i += NT) claim[i] = 0xFFFFFFFFu;
  for (int v = tid; v < NV; v += NT) {
    const unsigned kc = bitsToKey(__float_as_uint(img[v]));
    const int r = v / W_, c = v - r * W_;
    unsigned b = 0;
    if (c > 0       && bitsToKey(__float_as_uint(img[v - 1]))  <= kc) b |= 1u;
    if (c < W_ - 1  && bitsToKey(__float_as_uint(img[v + 1]))  <= kc) b |= 2u;
    if (r > 0       && bitsToKey(__float_as_uint(img[v - W_])) <= kc) b |= 4u;
    if (r < H_ - 1  && bitsToKey(__float_as_uint(img[v + W_])) <= kc) b |= 8u;
    incB[v] = (unsigned char)b;
  }
  __syncthreads();

  // ---- P4: chunked parallel-commit Kruskal, 2 live events/thread (window 2048) ----
  // Protocol identical to the proven single-event chunked version: every
  // uncommitted event in the window chases + claims every round (rank
  // priority, epoch-versioned claims); win-check+commit after one barrier;
  // next round after the counting barrier. 5 windows instead of 9.
  double T = 0.0, S = 0.0;
  unsigned gr = 0;

  #define DECL_EV(Sfx) \
    int vid##Sfx = 0, nv##Sfx##0 = 0, nv##Sfx##1 = 0, nv##Sfx##2 = 0, nv##Sfx##3 = 0; \
    int x##Sfx##0 = 0, x##Sfx##1 = 0, x##Sfx##2 = 0, x##Sfx##3 = 0; \
    unsigned e##Sfx##0 = 0, e##Sfx##1 = 0, e##Sfx##2 = 0, e##Sfx##3 = 0; \
    bool in##Sfx##0 = false, in##Sfx##1 = false, in##Sfx##2 = false, in##Sfx##3 = false; \
    float vt##Sfx = 0.f;

  #define LOAD_EV(Sfx, tt) { \
    vid##Sfx = (int)Pa[tt]; vt##Sfx = keyToFloat(Ka[tt]); \
    const unsigned ib = incB[vid##Sfx]; \
    nv##Sfx##0 = vid##Sfx - 1; nv##Sfx##1 = vid##Sfx + 1; \
    nv##Sfx##2 = vid##Sfx - W_; nv##Sfx##3 = vid##Sfx + W_; \
    in##Sfx##0 = (ib & 1u) != 0u; in##Sfx##1 = (ib & 2u) != 0u; \
    in##Sfx##2 = (ib & 4u) != 0u; in##Sfx##3 = (ib & 8u) != 0u; \
    x##Sfx##0 = in##Sfx##0 ? nv##Sfx##0 : vid##Sfx; \
    x##Sfx##1 = in##Sfx##1 ? nv##Sfx##1 : vid##Sfx; \
    x##Sfx##2 = in##Sfx##2 ? nv##Sfx##2 : vid##Sfx; \
    x##Sfx##3 = in##Sfx##3 ? nv##Sfx##3 : vid##Sfx; \
    e##Sfx##0 = e##Sfx##1 = e##Sfx##2 = e##Sfx##3 = 0; }

  #define CHASE_COMPRESS(Sfx) { \
    bool d0 = !in##Sfx##0, d1 = !in##Sfx##1, d2 = !in##Sfx##2, d3 = !in##Sfx##3; \
    while (!(d0 && d1 && d2 && d3)) { \
      if (!d0) { unsigned e = parU[x##Sfx##0]; if (e & 0x8000u) { e##Sfx##0 = e; d0 = true; } else x##Sfx##0 = (int)e; } \
      if (!d1) { unsigned e = parU[x##Sfx##1]; if (e & 0x8000u) { e##Sfx##1 = e; d1 = true; } else x##Sfx##1 = (int)e; } \
      if (!d2) { unsigned e = parU[x##Sfx##2]; if (e & 0x8000u) { e##Sfx##2 = e; d2 = true; } else x##Sfx##2 = (int)e; } \
      if (!d3) { unsigned e = parU[x##Sfx##3]; if (e & 0x8000u) { e##Sfx##3 = e; d3 = true; } else x##Sfx##3 = (int)e; } \
    } \
    if (in##Sfx##0 && nv##Sfx##0 != x##Sfx##0) parU[nv##Sfx##0] = (unsigned short)x##Sfx##0; \
    if (in##Sfx##1 && nv##Sfx##1 != x##Sfx##1) parU[nv##Sfx##1] = (unsigned short)x##Sfx##1; \
    if (in##Sfx##2 && nv##Sfx##2 != x##Sfx##2) parU[nv##Sfx##2] = (unsigned short)x##Sfx##2; \
    if (in##Sfx##3 && nv##Sfx##3 != x##Sfx##3) parU[nv##Sfx##3] = (unsigned short)x##Sfx##3; }

  for (int w = 0; w < 5; ++w) {
    const int base2 = w * 2048;
    const int tA = base2 + tid;
    const int tB = base2 + NT + tid;
    DECL_EV(A)
    DECL_EV(B)
    bool cmA = false, cmB = (tB >= NV);
    LOAD_EV(A, tA)
    if (!cmB) LOAD_EV(B, tB)

    for (;;) {
      const unsigned ep = (0x3FFFFu - gr) << 14;
      ++gr;
      const unsigned cvalA = ep | (unsigned)tA;
      const unsigned cvalB = ep | (unsigned)tB;
      bool uA0 = false, uA1 = false, uA2 = false, uA3 = false, uvA = false;
      bool uB0 = false, uB1 = false, uB2 = false, uB3 = false, uvB = false;
      int mvidA = 0, mvidB = 0;
      int rA0 = 0, rA1 = 0, rA2 = 0, rA3 = 0;
      int rB0 = 0, rB1 = 0, rB2 = 0, rB3 = 0;

      if (!cmA) {
        CHASE_COMPRESS(A)
        int mrank = tA; mvidA = vidA;
        rA0 = (int)(eA0 & 0x3FFFu); rA1 = (int)(eA1 & 0x3FFFu);
        rA2 = (int)(eA2 & 0x3FFFu); rA3 = (int)(eA3 & 0x3FFFu);
        if (inA0 && rA0 < mrank) { mrank = rA0; mvidA = xA0; }
        if (inA1 && rA1 < mrank) { mrank = rA1; mvidA = xA1; }
        if (inA2 && rA2 < mrank) { mrank = rA2; mvidA = xA2; }
        if (inA3 && rA3 < mrank) { mrank = rA3; mvidA = xA3; }
        uA0 = inA0 && (xA0 != mvidA);
        uA1 = inA1 && (xA1 != mvidA) && !(inA0 && xA1 == xA0);
        uA2 = inA2 && (xA2 != mvidA) && !(inA0 && xA2 == xA0) && !(inA1 && xA2 == xA1);
        uA3 = inA3 && (xA3 != mvidA) && !(inA0 && xA3 == xA0) && !(inA1 && xA3 == xA1) && !(inA2 && xA3 == xA2);
        uvA = (mvidA != vidA);
        if (uA0) atomicMin(&claim[xA0], cvalA);
        if (uA1) atomicMin(&claim[xA1], cvalA);
        if (uA2) atomicMin(&claim[xA2], cvalA);
        if (uA3) atomicMin(&claim[xA3], cvalA);
        if (uvA) atomicMin(&claim[vidA], cvalA);
      }
      if (!cmB) {
        CHASE_COMPRESS(B)
        int mrank = tB; mvidB = vidB;
        rB0 = (int)(eB0 & 0x3FFFu); rB1 = (int)(eB1 & 0x3FFFu);
        rB2 = (int)(eB2 & 0x3FFFu); rB3 = (int)(eB3 & 0x3FFFu);
        if (inB0 && rB0 < mrank) { mrank = rB0; mvidB = xB0; }
        if (inB1 && rB1 < mrank) { mrank = rB1; mvidB = xB1; }
        if (inB2 && rB2 < mrank) { mrank = rB2; mvidB = xB2; }
        if (inB3 && rB3 < mrank) { mrank = rB3; mvidB = xB3; }
        uB0 = inB0 && (xB0 != mvidB);
        uB1 = inB1 && (xB1 != mvidB) && !(inB0 && xB1 == xB0);
        uB2 = inB2 && (xB2 != mvidB) && !(inB0 && xB2 == xB0) && !(inB1 && xB2 == xB1);
        uB3 = inB3 && (xB3 != mvidB) && !(inB0 && xB3 == xB0) && !(inB1 && xB3 == xB1) && !(inB2 && xB3 == xB2);
        uvB = (mvidB != vidB);
        if (uB0) atomicMin(&claim[xB0], cvalB);
        if (uB1) atomicMin(&claim[xB1], cvalB);
        if (uB2) atomicMin(&claim[xB2], cvalB);
        if (uB3) atomicMin(&claim[xB3], cvalB);
        if (uvB) atomicMin(&claim[vidB], cvalB);
      }
      __syncthreads();                      // claims visible
      if (!cmA) {
        bool win = true;
        if (uA0 && claim[xA0] != cvalA) win = false;
        if (uA1 && claim[xA1] != cvalA) win = false;
        if (uA2 && claim[xA2] != cvalA) win = false;
        if (uA3 && claim[xA3] != cvalA) win = false;
        if (uvA && claim[vidA] != cvalA) win = false;
        if (win) {
          if (uA0) { const float p = vtA - keyToFloat(Ka[rA0]);
                     if (p > 0.0f) { T += (double)p; S += (double)(p * logf(p)); }
                     parU[xA0] = (unsigned short)mvidA; }
          if (uA1) { const float p = vtA - keyToFloat(Ka[rA1]);
                     if (p > 0.0f) { T += (double)p; S += (double)(p * logf(p)); }
                     parU[xA1] = (unsigned short)mvidA; }
          if (uA2) { const float p = vtA - keyToFloat(Ka[rA2]);
                     if (p > 0.0f) { T += (double)p; S += (double)(p * logf(p)); }
                     parU[xA2] = (unsigned short)mvidA; }
          if (uA3) { const float p = vtA - keyToFloat(Ka[rA3]);
                     if (p > 0.0f) { T += (double)p; S += (double)(p * logf(p)); }
                     parU[xA3] = (unsigned short)mvidA; }
          if (uvA) parU[vidA] = (unsigned short)mvidA;
          cmA = true;
        }
      }
      if (!cmB) {
        bool win = true;
        if (uB0 && claim[xB0] != cvalB) win = false;
        if (uB1 && claim[xB1] != cvalB) win = false;
        if (uB2 && claim[xB2] != cvalB) win = false;
        if (uB3 && claim[xB3] != cvalB) win = false;
        if (uvB && claim[vidB] != cvalB) win = false;
        if (win) {
          if (uB0) { const float p = vtB - keyToFloat(Ka[rB0]);
                     if (p > 0.0f) { T += (double)p; S += (double)(p * logf(p)); }
                     parU[xB0] = (unsigned short)mvidB; }
          if (uB1) { const float p = vtB - keyToFloat(Ka[rB1]);
                     if (p > 0.0f) { T += (double)p; S += (double)(p * logf(p)); }
                     parU[xB1] = (unsigned short)mvidB; }
          if (uB2) { const float p = vtB - keyToFloat(Ka[rB2]);
                     if (p > 0.0f) { T += (double)p; S += (double)(p * logf(p)); }
                     parU[xB2] = (unsigned short)mvidB; }
          if (uB3) { const float p = vtB - keyToFloat(Ka[rB3]);
                     if (p > 0.0f) { T += (double)p; S += (double)(p * logf(p)); }
                     parU[xB3] = (unsigned short)mvidB; }
          if (uvB) parU[vidB] = (unsigned short)mvidB;
          cmB = true;
        }
      }
      if (__syncthreads_count((cmA ? 0 : 1) + (cmB ? 0 : 1)) == 0) break;
    }
  }
  #undef DECL_EV
  #undef LOAD_EV
  #undef CHASE_COMPRESS

  // ---- P5: block reduction of entropy accumulators ----
  #pragma unroll
  for (int off = 32; off > 0; off >>= 1) {
    T += __shfl_down(T, off, 64);
    S += __shfl_down(S, off, 64);
  }
  if (ln == 0) { Td[wv] = T; Sd[wv] = S; }
  __syncthreads();
  if (tid == 0) {
    double Tt = 0.0, St = 0.0;
    for (int q = 0; q < 16; ++q) { Tt += Td[q]; St += Sd[q]; }
    out[blockIdx.x] = (Tt > 0.0) ? (float)(log(Tt) - St / Tt) : 0.0f;
  }
}

extern "C" void kernel_launch(void* const* d_in, const int* in_sizes, int n_in,
                              void* d_out, int out_size, void* d_ws, size_t ws_size,
                              hipStream_t stream) {
  (void)n_in; (void)out_size; (void)d_ws; (void)ws_size;
  const float* x = (const float*)d_in[0];
  float* out = (float*)d_out;
  int n_img = in_sizes[0] / NV;   // 64
  if (n_img <= 0) n_img = 1;
  topo_pk<<<n_img, NT, 0, stream>>>(x, out);
}